// Round 6
// baseline (250.706 us; speedup 1.0000x reference)
//
#include <hip/hip_runtime.h>

typedef float  f32x4  __attribute__((ext_vector_type(4)));
typedef float  f32x2  __attribute__((ext_vector_type(2)));
typedef short  bf16x8 __attribute__((ext_vector_type(8)));

#define TWOLOG2E   2.8853900817779268f
#define NLOG2E    -1.4426950408889634f
#define NTWOLOG2E -2.8853900817779268f

__device__ __forceinline__ unsigned short f2b(float f) {      // fp32 -> bf16 RNE
    unsigned int u = __builtin_bit_cast(unsigned int, f);
    u += 0x7fffu + ((u >> 16) & 1u);
    return (unsigned short)(u >> 16);
}
__device__ __forceinline__ float b2f(unsigned short s) {
    unsigned int u = ((unsigned int)s) << 16;
    return __builtin_bit_cast(float, u);
}
__device__ __forceinline__ unsigned int pk2(float lo, float hi) {
#if __has_builtin(__builtin_amdgcn_cvt_pk_bf16_f32)
    typedef __bf16 bf16x2 __attribute__((ext_vector_type(2)));
    bf16x2 p = __builtin_amdgcn_cvt_pk_bf16_f32(lo, hi);
    return __builtin_bit_cast(unsigned int, p);
#else
    return (unsigned int)f2b(lo) | ((unsigned int)f2b(hi) << 16);
#endif
}
__device__ __forceinline__ float frcp(float x) { return __builtin_amdgcn_rcpf(x); }
__device__ __forceinline__ float fex2(float x) { return __builtin_amdgcn_exp2f(x); }

// R19: ILP-for-TLP swap. R14-R18 all land 165-175us with VALUBusy*dur ~ const
// and ~42% issue-idle: the two co-resident waves (2 blocks/CU) phase-lock on
// the per-SIMD trans unit (epilogue bursts serialize, then both idle through
// the read/MFMA phase — a self-synchronizing convoy). Fix: 64 rows/block,
// grid 256 = 1 block/CU = 1 wave/SIMD, each wave does 4 independent 16-batch
// tiles per cell_step (2x work, 8 independent epilogue chains + 32 MFMA in
// one straight-line stream) so the COMPILER statically overlaps tile B's
// MFMA/reads with tile A's trans latency. 1 wave/SIMD -> 512 unified regs:
// afr 64 + cbq 32 + hreg 16 + cp2 32 + acc 32-64 + temps fits, no spill.
// LDS 80KB/block (hb 64KB + xb 16KB) - gfx950 allows up to 160KB/WG.
// Carries R18's transposed orientation: gates^T = W*h^T (W=A, h=B);
// RowMap(g,w): unit=8*(w>>2)+2*(g&3)+(w&1), gate=2*(g>>2)+((w>>1)&1);
// epilogue output pk2 words ARE the next B-frag (register recurrence);
// cross-layer handoff = linear conflict-free ds_write/read_b128.
// Epilogue per unit (floor per R14/R16/R17: 5 exp2 + 2 rcp, packed f32x2):
//   p1=(1+ei)(1+eg); cn' = [cp*p1 - 2log2e(1-eg)(1+ef)] * rcp(p1*(1+ef))
//   (cp = -2log2e*c);  ec = exp2(cp);  h = (1-ec)*rcp((1+eo)(1+ec))
__global__ __launch_bounds__(256, 1)
void lstm_mfma(const float* __restrict__ xg,  const float* __restrict__ Wih0,
               const float* __restrict__ Wih, const float* __restrict__ Whh,
               const float* __restrict__ bih, const float* __restrict__ bhh,
               const float* __restrict__ Wlin,const float* __restrict__ blin,
               float* __restrict__ out) {
    // hb: [l][parity][slot01] x (tile*256 + lane*4 + w) u32 = 16 slots x 4KB
    __shared__ unsigned int hb[16 * 1024] __attribute__((aligned(16)));
    __shared__ unsigned int xb[64 * 64];                    // [t][row] 2xbf16

    const int tid  = threadIdx.x;
    const int wv   = __builtin_amdgcn_readfirstlane(tid >> 6);  // layer id, uniform
    const int lane = tid & 63;
    const int m    = lane & 15;    // batch index within 16-tile (B col / D col)
    const int q    = lane >> 4;    // quad: unit octet 8q..8q+7, k-chunk q*8..
    const int row0 = blockIdx.x * 64;

    // stage x -> LDS bf16 [t][row]
    for (int i = tid; i < 4096; i += 256) {
        int r = i >> 6, t = i & 63;
        float x0 = xg[(size_t)(row0 + r) * 192 + t];
        float x1 = xg[(size_t)(row0 + r) * 192 + 64 + t];
        xb[t * 64 + r] = pk2(x0, x1);
    }

    // ---- one-time gather of A-frags (weights) + bias quads ----
    // A-frag lane (m,q): A[row m][k q*8+j] = W[RowMap(g,m)][k], scaled.
    bf16x8 afr[2][8];   // [src: 0=input (Wih), 1=recurrent (Whh)][g]
    f32x4  cbq[8];      // bias C quads: element r = row q*4+r = RowMap(g,q*4+r)
#pragma unroll
    for (int g = 0; g < 8; ++g) {
        const int   u_m  = 8 * (m >> 2) + 2 * (g & 3) + (m & 1);
        const int   gt_m = 2 * (g >> 2) + ((m >> 1) & 1);
        const int   rowG = gt_m * 32 + u_m;
        const float sc   = (gt_m == 2) ? NTWOLOG2E : NLOG2E;
        // input-source frag
        {
            float w[8];
            if (wv == 0) {
#pragma unroll
                for (int jj = 0; jj < 8; ++jj) w[jj] = 0.0f;
                if (q == 0) { w[0] = Wih0[rowG * 2]; w[1] = Wih0[rowG * 2 + 1]; }
            } else {
                const float* src = Wih + (wv - 1) * 4096 + rowG * 32 + q * 8;
#pragma unroll
                for (int jj = 0; jj < 8; ++jj) w[jj] = src[jj];
            }
            bf16x8 fr;
#pragma unroll
            for (int jj = 0; jj < 8; ++jj) fr[jj] = (short)f2b(w[jj] * sc);
            afr[0][g] = fr;
        }
        // recurrent frag
        {
            const float* src = Whh + wv * 4096 + rowG * 32 + q * 8;
            bf16x8 fr;
#pragma unroll
            for (int jj = 0; jj < 8; ++jj) fr[jj] = (short)f2b(src[jj] * sc);
            afr[1][g] = fr;
        }
        // bias quad (per D row q*4+r)
        f32x4 c4;
#pragma unroll
        for (int r = 0; r < 4; ++r) {
            const int   u_r  = 8 * q + 2 * (g & 3) + (r & 1);
            const int   gt_r = 2 * (g >> 2) + ((r >> 1) & 1);
            const float scr  = (gt_r == 2) ? NTWOLOG2E : NLOG2E;
            c4[r] = (bih[wv * 128 + gt_r * 32 + u_r] + bhh[wv * 128 + gt_r * 32 + u_r]) * scr;
        }
        cbq[g] = c4;
    }

    // persistent register state: h as next-B-frag, scaled cell state
    bf16x8 hreg[4];     // [tile]; zero = h(0)=0
#pragma unroll
    for (int tt = 0; tt < 4; ++tt) {
        union { unsigned int u[4]; bf16x8 v; } z;
        z.u[0] = 0u; z.u[1] = 0u; z.u[2] = 0u; z.u[3] = 0u;
        hreg[tt] = z.v;
    }
    f32x2 cp2[4][4];    // -2log2e*c for unit pair (8q+2j, +1): [tile][j]
#pragma unroll
    for (int tt = 0; tt < 4; ++tt)
#pragma unroll
        for (int j = 0; j < 4; ++j) cp2[tt][j] = (f32x2){0.0f, 0.0f};

    __syncthreads();

    // packed LSTM epilogue chain for one unit-pair (f32x2)
    auto chain = [&](f32x2 ai, f32x2 af, f32x2 ag, f32x2 ao, f32x2& cpr) -> f32x2 {
        const f32x2 one = {1.0f, 1.0f};
        const f32x2 c2l = {TWOLOG2E, TWOLOG2E};
        const f32x2 n2l = {NTWOLOG2E, NTWOLOG2E};
        f32x2 ei = {fex2(ai.x), fex2(ai.y)};              // e^{-a_i}
        f32x2 ef = {fex2(af.x), fex2(af.y)};              // e^{-a_f}
        f32x2 eg = {fex2(ag.x), fex2(ag.y)};              // e^{-2 a_g}
        f32x2 eo = {fex2(ao.x), fex2(ao.y)};              // e^{-a_o}
        f32x2 apf = one + ef;
        f32x2 p1  = (one + ei) * (one + eg);
        f32x2 Dc  = p1 * apf;
        f32x2 R_  = {frcp(Dc.x), frcp(Dc.y)};
        f32x2 egp = __builtin_elementwise_fma(eg, c2l, n2l);  // -2log2e*(1-eg)
        f32x2 t1  = egp * apf;
        f32x2 t2  = __builtin_elementwise_fma(cpr, p1, t1);
        f32x2 cn  = t2 * R_;                              // scaled cell state
        cpr = cn;
        f32x2 ec  = {fex2(cn.x), fex2(cn.y)};             // e^{-2c}
        f32x2 Dh  = (one + eo) * (one + ec);
        f32x2 Rh  = {frcp(Dh.x), frcp(Dh.y)};
        return (one - ec) * Rh;
    };

    // one timestep for all 64 batch rows (4 x 16-batch tiles, independent)
    auto cell_step = [&](int t, const unsigned int* pin, unsigned int* pout) {
#pragma unroll
        for (int tt = 0; tt < 4; ++tt) {
            // input B-frag: x (wave 0) or layer-below h from LDS (layout-preserving)
            bf16x8 bin;
            if (wv == 0) {
                unsigned int xd = xb[t * 64 + tt * 16 + m];
                union { unsigned int u[4]; bf16x8 v; } au;
                au.u[0] = (q == 0) ? xd : 0u; au.u[1] = 0u; au.u[2] = 0u; au.u[3] = 0u;
                bin = au.v;
            } else {
                bin = *(const bf16x8*)(pin + tt * 256 + lane * 4);
            }
            f32x4 acc[8];
#pragma unroll
            for (int g = 0; g < 8; ++g) {
                acc[g] = __builtin_amdgcn_mfma_f32_16x16x32_bf16(afr[0][g], bin, cbq[g], 0, 0, 0);
                acc[g] = __builtin_amdgcn_mfma_f32_16x16x32_bf16(afr[1][g], hreg[tt], acc[g], 0, 0, 0);
            }
            // epilogue: 4 unit-pair chains; outputs form the next B-frag directly
            union { unsigned int u[4]; bf16x8 v; } hn;
#pragma unroll
            for (int j = 0; j < 4; ++j) {
                f32x2 ai = (f32x2)__builtin_shufflevector(acc[j],     acc[j],     0, 1); // gate i
                f32x2 af = (f32x2)__builtin_shufflevector(acc[j],     acc[j],     2, 3); // gate f
                f32x2 ag = (f32x2)__builtin_shufflevector(acc[4 + j], acc[4 + j], 0, 1); // gate g
                f32x2 ao = (f32x2)__builtin_shufflevector(acc[4 + j], acc[4 + j], 2, 3); // gate o
                f32x2 hh = chain(ai, af, ag, ao, cp2[tt][j]);
                hn.u[j] = pk2(hh.x, hh.y);
            }
            hreg[tt] = hn.v;                                   // register recurrence
            *(bf16x8*)(pout + tt * 256 + lane * 4) = hn.v;     // cross-layer handoff
        }
    };

    for (int S = 0; S < 35; ++S) {
        const int t0 = 2 * (S - wv);          // wave-uniform
        if (t0 >= 0 && t0 <= 62) {
            const int p  = S & 1;
            const int pb = p ^ 1;
            unsigned int*       Lc0 = hb + ((wv * 2 + p ) * 2    ) * 1024;  // own layer, cur parity, slot0
            unsigned int*       Lc1 = Lc0 + 1024;                            // slot1
            const int           lb  = (wv > 0) ? (wv - 1) : 0;
            const unsigned int* Dp0 = hb + ((lb * 2 + pb) * 2    ) * 1024;  // layer below, prev parity, slot0
            const unsigned int* Dp1 = Dp0 + 1024;                            // slot1

            cell_step(t0,     Dp0, Lc0);   // t0: input h_{l-1}(t0); recurrent = hreg
            cell_step(t0 + 1, Dp1, Lc1);   // t1: input h_{l-1}(t1); recurrent = hreg (updated)
        }
        __syncthreads();
    }

    // output head: h3(t=63) -> written by wave 3 at S=34 (p=0), slot1
    if (tid < 64) {
        const unsigned int* h3 = hb + ((3 * 2 + 0) * 2 + 1) * 1024;
        const int tt = tid >> 4, mm = tid & 15;
        float s = blin[0];
#pragma unroll
        for (int qq = 0; qq < 4; ++qq)
#pragma unroll
            for (int j = 0; j < 4; ++j) {
                unsigned int w2 = h3[tt * 256 + (qq * 16 + mm) * 4 + j];
                const int u0 = 8 * qq + 2 * j;
                s += Wlin[u0]     * b2f((unsigned short)(w2 & 0xffffu));
                s += Wlin[u0 + 1] * b2f((unsigned short)(w2 >> 16));
            }
        out[row0 + tid] = frcp(1.0f + fex2(s * NLOG2E));
    }
}

extern "C" void kernel_launch(void* const* d_in, const int* in_sizes, int n_in,
                              void* d_out, int out_size, void* d_ws, size_t ws_size,
                              hipStream_t stream) {
    const float* x    = (const float*)d_in[0];
    const float* Wih0 = (const float*)d_in[1];
    const float* Wih  = (const float*)d_in[2];
    const float* Whh  = (const float*)d_in[3];
    const float* bih  = (const float*)d_in[4];
    const float* bhh  = (const float*)d_in[5];
    const float* Wlin = (const float*)d_in[6];
    const float* blin = (const float*)d_in[7];
    float* out = (float*)d_out;

    lstm_mfma<<<256, 256, 0, stream>>>(x, Wih0, Wih, Whh, bih, bhh, Wlin, blin, out);
}

// Round 7
// 215.263 us; speedup vs baseline: 1.1647x; 1.1647x over previous
//
#include <hip/hip_runtime.h>

typedef float  f32x4  __attribute__((ext_vector_type(4)));
typedef float  f32x2  __attribute__((ext_vector_type(2)));
typedef short  bf16x8 __attribute__((ext_vector_type(8)));

#define TWOLOG2E   2.8853900817779268f
#define NLOG2E    -1.4426950408889634f
#define NTWOLOG2E -2.8853900817779268f

__device__ __forceinline__ unsigned short f2b(float f) {      // fp32 -> bf16 RNE
    unsigned int u = __builtin_bit_cast(unsigned int, f);
    u += 0x7fffu + ((u >> 16) & 1u);
    return (unsigned short)(u >> 16);
}
__device__ __forceinline__ float b2f(unsigned short s) {
    unsigned int u = ((unsigned int)s) << 16;
    return __builtin_bit_cast(float, u);
}
__device__ __forceinline__ unsigned int pk2(float lo, float hi) {
#if __has_builtin(__builtin_amdgcn_cvt_pk_bf16_f32)
    typedef __bf16 bf16x2 __attribute__((ext_vector_type(2)));
    bf16x2 p = __builtin_amdgcn_cvt_pk_bf16_f32(lo, hi);
    return __builtin_bit_cast(unsigned int, p);
#else
    return (unsigned int)f2b(lo) | ((unsigned int)f2b(hi) << 16);
#endif
}
__device__ __forceinline__ float frcp(float x) { return __builtin_amdgcn_rcpf(x); }
__device__ __forceinline__ float fex2(float x) { return __builtin_amdgcn_exp2f(x); }

// R20: stage-split (SoA) epilogue on the R18 base. Diagnosis from R19: per-wave
// issue density is ~30% regardless of TLP/ILP config because the compiler
// register-minimizes (VGPR 92-100 of 256 available) — the 4 independent j-chains
// share temp registers, so WAR/WAW false deps serialize them and each chain's
// ~60cyc trans critical path is exposed. Fix: epilogue restructured stage-wise
// with DISTINCT array storage per stage variable (ei/ef/eg/eo/p1/apf/R_/cn/ec
// [4] each): stage 1 issues 32 independent v_exp back-to-back, later stages
// 4-8 independent ops each — scheduler can pipeline the trans unit. Costs ~60
// extra live regs (budget 256/wave at 2 waves/SIMD — never used until now).
// Carries R18: transposed GEMM gates^T = W·h^T (W=A, h=B); RowMap(g,w):
// unit=8*(w>>2)+2*(g&3)+(w&1), gate=2*(g>>2)+((w>>1)&1); epilogue pk2 words
// ARE the next B-frag (register recurrence); cross-layer = linear ds_*_b128
// conflict-free; bias in MFMA C (cbq); weights pre-scaled -log2e/-2log2e.
// Pipeline: 32 rows/block, grid 512, 2 blocks/CU, wave l = layer l, 2-t
// supersteps, 35 barriers. Per-unit math (floor: 5 exp2 + 2 rcp):
//   p1=(1+ei)(1+eg); cn' = [cp*p1 - 2log2e(1-eg)(1+ef)] * rcp(p1*(1+ef))
//   (cp = -2log2e*c);  ec = exp2(cp);  h = (1-ec)*rcp((1+eo)(1+ec))
// History: R15 4-wave spills; R16 manual overlap +movs; R17 row-pairing
// neutral; R19 1-wave ILP -> AGPR tax. Health: FETCH ~4.6MB, WRITE ~64KB.
__global__ __launch_bounds__(256, 2)
void lstm_mfma(const float* __restrict__ xg,  const float* __restrict__ Wih0,
               const float* __restrict__ Wih, const float* __restrict__ Whh,
               const float* __restrict__ bih, const float* __restrict__ bhh,
               const float* __restrict__ Wlin,const float* __restrict__ blin,
               float* __restrict__ out) {
    // hb: [l][parity][slot01] x (tt*256 + lane*4 + w) u32  = 16 slots x 2KB
    __shared__ unsigned int hb[16 * 512] __attribute__((aligned(16)));
    __shared__ unsigned int xb[64 * 32];                    // [t][row] 2xbf16

    const int tid  = threadIdx.x;
    const int wv   = __builtin_amdgcn_readfirstlane(tid >> 6);  // layer id, uniform
    const int lane = tid & 63;
    const int m    = lane & 15;    // batch index within 16-tile (B col / D col)
    const int q    = lane >> 4;    // quad: unit octet 8q..8q+7, k-chunk q*8..
    const int row0 = blockIdx.x * 32;

    // stage x -> LDS bf16 [t][row]
    for (int i = tid; i < 2048; i += 256) {
        int r = i >> 6, t = i & 63;
        float x0 = xg[(size_t)(row0 + r) * 192 + t];
        float x1 = xg[(size_t)(row0 + r) * 192 + 64 + t];
        xb[t * 32 + r] = pk2(x0, x1);
    }

    // ---- one-time gather of A-frags (weights) + bias quads ----
    bf16x8 afr[2][8];   // [src: 0=input (Wih), 1=recurrent (Whh)][g]
    f32x4  cbq[8];      // bias C quads: element r = row q*4+r
#pragma unroll
    for (int g = 0; g < 8; ++g) {
        const int   u_m  = 8 * (m >> 2) + 2 * (g & 3) + (m & 1);
        const int   gt_m = 2 * (g >> 2) + ((m >> 1) & 1);
        const int   rowG = gt_m * 32 + u_m;
        const float sc   = (gt_m == 2) ? NTWOLOG2E : NLOG2E;
        {
            float w[8];
            if (wv == 0) {
#pragma unroll
                for (int jj = 0; jj < 8; ++jj) w[jj] = 0.0f;
                if (q == 0) { w[0] = Wih0[rowG * 2]; w[1] = Wih0[rowG * 2 + 1]; }
            } else {
                const float* src = Wih + (wv - 1) * 4096 + rowG * 32 + q * 8;
#pragma unroll
                for (int jj = 0; jj < 8; ++jj) w[jj] = src[jj];
            }
            bf16x8 fr;
#pragma unroll
            for (int jj = 0; jj < 8; ++jj) fr[jj] = (short)f2b(w[jj] * sc);
            afr[0][g] = fr;
        }
        {
            const float* src = Whh + wv * 4096 + rowG * 32 + q * 8;
            bf16x8 fr;
#pragma unroll
            for (int jj = 0; jj < 8; ++jj) fr[jj] = (short)f2b(src[jj] * sc);
            afr[1][g] = fr;
        }
        f32x4 c4;
#pragma unroll
        for (int r = 0; r < 4; ++r) {
            const int   u_r  = 8 * q + 2 * (g & 3) + (r & 1);
            const int   gt_r = 2 * (g >> 2) + ((r >> 1) & 1);
            const float scr  = (gt_r == 2) ? NTWOLOG2E : NLOG2E;
            c4[r] = (bih[wv * 128 + gt_r * 32 + u_r] + bhh[wv * 128 + gt_r * 32 + u_r]) * scr;
        }
        cbq[g] = c4;
    }

    // persistent register state: h as next-B-frag, scaled cell state
    bf16x8 hreg[2];     // [tt]; zero = h(0)=0
#pragma unroll
    for (int tt = 0; tt < 2; ++tt) {
        union { unsigned int u[4]; bf16x8 v; } z;
        z.u[0] = 0u; z.u[1] = 0u; z.u[2] = 0u; z.u[3] = 0u;
        hreg[tt] = z.v;
    }
    f32x2 cp2[2][4];    // -2log2e*c for unit pair (8q+2j, +1): [tt][j]
#pragma unroll
    for (int tt = 0; tt < 2; ++tt)
#pragma unroll
        for (int j = 0; j < 4; ++j) cp2[tt][j] = (f32x2){0.0f, 0.0f};

    __syncthreads();

    const f32x2 one = {1.0f, 1.0f};
    const f32x2 c2l = {TWOLOG2E, TWOLOG2E};
    const f32x2 n2l = {NTWOLOG2E, NTWOLOG2E};

    // one timestep for all 32 batch rows (2 x 16-batch tiles)
    auto cell_step = [&](int t, const unsigned int* pin, unsigned int* pout) {
#pragma unroll
        for (int tt = 0; tt < 2; ++tt) {
            // input B-frag: x (wave 0) or layer-below h from LDS (layout-preserving)
            bf16x8 bin;
            if (wv == 0) {
                unsigned int xd = xb[t * 32 + tt * 16 + m];
                union { unsigned int u[4]; bf16x8 v; } au;
                au.u[0] = (q == 0) ? xd : 0u; au.u[1] = 0u; au.u[2] = 0u; au.u[3] = 0u;
                bin = au.v;
            } else {
                bin = *(const bf16x8*)(pin + tt * 256 + lane * 4);
            }
            f32x4 acc[8];
#pragma unroll
            for (int g = 0; g < 8; ++g) {
                acc[g] = __builtin_amdgcn_mfma_f32_16x16x32_bf16(afr[0][g], bin, cbq[g], 0, 0, 0);
                acc[g] = __builtin_amdgcn_mfma_f32_16x16x32_bf16(afr[1][g], hreg[tt], acc[g], 0, 0, 0);
            }

            // ---- SoA stage-split epilogue: distinct storage per stage var ----
            // stage 1: 32 independent v_exp (gate preactivations, negated-scaled)
            f32x2 ei[4], ef[4], eg[4], eo[4];
#pragma unroll
            for (int j = 0; j < 4; ++j) {
                f32x2 ai = (f32x2)__builtin_shufflevector(acc[j],     acc[j],     0, 1);
                f32x2 af = (f32x2)__builtin_shufflevector(acc[j],     acc[j],     2, 3);
                f32x2 ag = (f32x2)__builtin_shufflevector(acc[4 + j], acc[4 + j], 0, 1);
                f32x2 ao = (f32x2)__builtin_shufflevector(acc[4 + j], acc[4 + j], 2, 3);
                ei[j] = (f32x2){fex2(ai.x), fex2(ai.y)};      // e^{-a_i}
                ef[j] = (f32x2){fex2(af.x), fex2(af.y)};      // e^{-a_f}
                eg[j] = (f32x2){fex2(ag.x), fex2(ag.y)};      // e^{-2 a_g}
                eo[j] = (f32x2){fex2(ao.x), fex2(ao.y)};      // e^{-a_o}
            }
            // stage 2: denominators + 8 independent rcp
            f32x2 apf[4], p1[4], R_[4];
#pragma unroll
            for (int j = 0; j < 4; ++j) {
                apf[j] = one + ef[j];
                p1[j]  = (one + ei[j]) * (one + eg[j]);
                f32x2 Dc = p1[j] * apf[j];
                R_[j]  = (f32x2){frcp(Dc.x), frcp(Dc.y)};
            }
            // stage 3: cell update (packed fma chains, independent across j)
            f32x2 cn[4];
#pragma unroll
            for (int j = 0; j < 4; ++j) {
                f32x2 egp = __builtin_elementwise_fma(eg[j], c2l, n2l);   // -2log2e*(1-eg)
                f32x2 t2  = __builtin_elementwise_fma(cp2[tt][j], p1[j], egp * apf[j]);
                cn[j] = t2 * R_[j];
                cp2[tt][j] = cn[j];
            }
            // stage 4: 8 independent v_exp (cell nonlinearity)
            f32x2 ec[4];
#pragma unroll
            for (int j = 0; j < 4; ++j) ec[j] = (f32x2){fex2(cn[j].x), fex2(cn[j].y)};
            // stage 5: h denominators + 8 independent rcp + pack
            union { unsigned int u[4]; bf16x8 v; } hn;
#pragma unroll
            for (int j = 0; j < 4; ++j) {
                f32x2 Dh = (one + eo[j]) * (one + ec[j]);
                f32x2 Rh = (f32x2){frcp(Dh.x), frcp(Dh.y)};
                f32x2 hh = (one - ec[j]) * Rh;
                hn.u[j] = pk2(hh.x, hh.y);
            }
            hreg[tt] = hn.v;                                   // register recurrence
            *(bf16x8*)(pout + tt * 256 + lane * 4) = hn.v;     // cross-layer handoff
        }
    };

    for (int S = 0; S < 35; ++S) {
        const int t0 = 2 * (S - wv);          // wave-uniform
        if (t0 >= 0 && t0 <= 62) {
            const int p  = S & 1;
            const int pb = p ^ 1;
            unsigned int*       Lc0 = hb + ((wv * 2 + p ) * 2    ) * 512;  // own layer, cur parity, slot0
            unsigned int*       Lc1 = Lc0 + 512;                            // slot1
            const int           lb  = (wv > 0) ? (wv - 1) : 0;
            const unsigned int* Dp0 = hb + ((lb * 2 + pb) * 2    ) * 512;  // layer below, prev parity, slot0
            const unsigned int* Dp1 = Dp0 + 512;                            // slot1

            cell_step(t0,     Dp0, Lc0);   // t0: input h_{l-1}(t0); recurrent = hreg
            cell_step(t0 + 1, Dp1, Lc1);   // t1: input h_{l-1}(t1); recurrent = hreg (updated)
        }
        __syncthreads();
    }

    // output head: h3(t=63) -> written by wave 3 at S=34 (p=0), slot1
    if (tid < 32) {
        const unsigned int* h3 = hb + ((3 * 2 + 0) * 2 + 1) * 512;
        const int tt = tid >> 4, mm = tid & 15;
        float s = blin[0];
#pragma unroll
        for (int qq = 0; qq < 4; ++qq)
#pragma unroll
            for (int j = 0; j < 4; ++j) {
                unsigned int w2 = h3[tt * 256 + (qq * 16 + mm) * 4 + j];
                const int u0 = 8 * qq + 2 * j;
                s += Wlin[u0]     * b2f((unsigned short)(w2 & 0xffffu));
                s += Wlin[u0 + 1] * b2f((unsigned short)(w2 >> 16));
            }
        out[row0 + tid] = frcp(1.0f + fex2(s * NLOG2E));
    }
}

extern "C" void kernel_launch(void* const* d_in, const int* in_sizes, int n_in,
                              void* d_out, int out_size, void* d_ws, size_t ws_size,
                              hipStream_t stream) {
    const float* x    = (const float*)d_in[0];
    const float* Wih0 = (const float*)d_in[1];
    const float* Wih  = (const float*)d_in[2];
    const float* Whh  = (const float*)d_in[3];
    const float* bih  = (const float*)d_in[4];
    const float* bhh  = (const float*)d_in[5];
    const float* Wlin = (const float*)d_in[6];
    const float* blin = (const float*)d_in[7];
    float* out = (float*)d_out;

    lstm_mfma<<<512, 256, 0, stream>>>(x, Wih0, Wih, Whh, bih, bhh, Wlin, blin, out);
}